// Round 1
// baseline (459.253 us; speedup 1.0000x reference)
//
#include <hip/hip_runtime.h>

#define BB 512
#define SS 1024
#define TT 64

__device__ __forceinline__ float wmax64(float v) {
#pragma unroll
  for (int off = 32; off > 0; off >>= 1) v = fmaxf(v, __shfl_xor(v, off, 64));
  return v;
}
__device__ __forceinline__ float wsum64(float v) {
#pragma unroll
  for (int off = 32; off > 0; off >>= 1) v += __shfl_xor(v, off, 64);
  return v;
}

// ---------------- gold score ----------------
__global__ void gold_kernel(const float* __restrict__ em, const int* __restrict__ tags,
                            const float* __restrict__ mask, const float* __restrict__ trans,
                            float* __restrict__ gold) {
  const int b = blockIdx.x;
  const int tid = threadIdx.x;
  const int* tg = tags + b * SS;
  const float* mkb = mask + b * SS;
  const float* emb = em + (size_t)b * SS * TT;
  float part = 0.f;
  for (int s = tid; s < SS; s += 256) {
    int t1 = tg[s];
    float e = emb[s * TT + t1];
    if (s == 0) {
      part = fmaf(e, mkb[0], part);
    } else {
      int t0 = tg[s - 1];
      part = fmaf(trans[t1 * TT + t0] + e, mkb[s], part);
    }
  }
  part = wsum64(part);
  __shared__ float red[4];
  if ((tid & 63) == 0) red[tid >> 6] = part;
  __syncthreads();
  if (tid == 0) gold[b] = (red[0] + red[1]) + (red[2] + red[3]);
}

// ---------------- partition: fwd/bwd meet-in-the-middle ----------------
// One step of the recurrence in linear space with per-step max normalization.
// DIR==0 (fwd):  x'_j = max + log(sum_i exp(x_i - max) * E[i][j]) + e_j*mk
// DIR==1 (bwd):  t_j = x_j + e_j*mk;  x'_i = max + log(sum_j E[i][j] * exp(t_j - max))
#define CRF_STEP(xv, ev, mkv)                                                        \
  ({                                                                                 \
    float t_ = (DIR == 1) ? fmaf((ev), (mkv), (xv)) : (xv);                          \
    float m_ = wmax64(t_);                                                           \
    float p_ = __expf(t_ - m_);                                                      \
    int pb_ = __float_as_int(p_);                                                    \
    float a0_ = 0.f, a1_ = 0.f, a2_ = 0.f, a3_ = 0.f;                                \
    _Pragma("unroll") for (int i_ = 0; i_ < TT; i_ += 4) {                           \
      a0_ = fmaf(__int_as_float(__builtin_amdgcn_readlane(pb_, i_ + 0)), E[i_ + 0], a0_); \
      a1_ = fmaf(__int_as_float(__builtin_amdgcn_readlane(pb_, i_ + 1)), E[i_ + 1], a1_); \
      a2_ = fmaf(__int_as_float(__builtin_amdgcn_readlane(pb_, i_ + 2)), E[i_ + 2], a2_); \
      a3_ = fmaf(__int_as_float(__builtin_amdgcn_readlane(pb_, i_ + 3)), E[i_ + 3], a3_); \
    }                                                                                \
    float nx_ = m_ + __logf((a0_ + a1_) + (a2_ + a3_));                              \
    if (DIR == 0) nx_ = fmaf((ev), (mkv), nx_);                                      \
    nx_;                                                                             \
  })

template <int DIR>
__device__ __forceinline__ void part_run(int b, int lane, const float* __restrict__ em,
                                         const float* __restrict__ mask,
                                         const float* __restrict__ sh,
                                         float* __restrict__ outv) {
  // Per-lane E fragment: fwd lane j holds column j (over i); bwd lane i holds row i (over j).
  float E[TT];
#pragma unroll
  for (int i = 0; i < TT; i++)
    E[i] = __expf(DIR == 0 ? sh[i * TT + lane] : sh[lane * TT + i]);

  const float* emb = em + (size_t)b * SS * TT;
  const float* mkb = mask + b * SS;

  float x = (DIR == 0) ? emb[lane] * mkb[0] : 0.f;

  const int NST = (DIR == 0) ? (SS / 2 - 1) : (SS / 2);  // fwd: s=1..511, bwd: s=1023..512
  const int s0 = (DIR == 0) ? 1 : (SS - 1);
  const int sd = (DIR == 0) ? 1 : -1;

  // 4-deep emission prefetch (coalesced: lane j reads em[b][s][j])
  float eb0 = emb[(s0 + 0 * sd) * TT + lane];
  float eb1 = emb[(s0 + 1 * sd) * TT + lane];
  float eb2 = emb[(s0 + 2 * sd) * TT + lane];
  float eb3 = emb[(s0 + 3 * sd) * TT + lane];

  int n = 0;
  for (; n + 4 <= NST; n += 4) {
    // prefetch indices stay in [0, S-1]: fwd max 512, bwd min 508
    {
      float e = eb0;
      eb0 = emb[(s0 + sd * (n + 4)) * TT + lane];
      x = CRF_STEP(x, e, mkb[s0 + sd * (n + 0)]);
    }
    {
      float e = eb1;
      eb1 = emb[(s0 + sd * (n + 5)) * TT + lane];
      x = CRF_STEP(x, e, mkb[s0 + sd * (n + 1)]);
    }
    {
      float e = eb2;
      eb2 = emb[(s0 + sd * (n + 6)) * TT + lane];
      x = CRF_STEP(x, e, mkb[s0 + sd * (n + 2)]);
    }
    {
      float e = eb3;
      eb3 = emb[(s0 + sd * (n + 7)) * TT + lane];
      x = CRF_STEP(x, e, mkb[s0 + sd * (n + 3)]);
    }
  }
  for (; n < NST; n++) {
    float e = emb[(s0 + sd * n) * TT + lane];
    x = CRF_STEP(x, e, mkb[s0 + sd * n]);
  }

  outv[b * TT + lane] = x;
}

__global__ void __launch_bounds__(64, 1)
    part_kernel(const float* __restrict__ em, const float* __restrict__ mask,
                const float* __restrict__ trans, float* __restrict__ alpha,
                float* __restrict__ beta) {
  __shared__ float sh[TT * TT];
  const int lane = threadIdx.x;
  for (int k = lane; k < TT * TT; k += 64) sh[k] = trans[k];
  __syncthreads();
  const int dir = blockIdx.x & 1;
  const int b = blockIdx.x >> 1;
  if (dir == 0)
    part_run<0>(b, lane, em, mask, sh, alpha);
  else
    part_run<1>(b, lane, em, mask, sh, beta);
}

// ---------------- combine: Z_b = lse(alpha+beta); out = mean(Z - gold) ----------------
__global__ void combine_kernel(const float* __restrict__ alpha, const float* __restrict__ beta,
                               const float* __restrict__ gold, float* __restrict__ out) {
  const int b = blockIdx.x;
  const int j = threadIdx.x;
  float v = alpha[b * TT + j] + beta[b * TT + j];
  float m = wmax64(v);
  float e = __expf(v - m);
  e = wsum64(e);
  if (j == 0) {
    float Z = m + __logf(e);
    atomicAdd(out, (Z - gold[b]) * (1.0f / (float)BB));
  }
}

extern "C" void kernel_launch(void* const* d_in, const int* in_sizes, int n_in,
                              void* d_out, int out_size, void* d_ws, size_t ws_size,
                              hipStream_t stream) {
  const float* em = (const float*)d_in[0];
  const int* tags = (const int*)d_in[1];
  const float* mask = (const float*)d_in[2];
  const float* trans = (const float*)d_in[3];
  float* out = (float*)d_out;

  float* alpha = (float*)d_ws;        // 512*64 floats
  float* beta = alpha + BB * TT;      // 512*64 floats
  float* gold = beta + BB * TT;       // 512 floats

  hipMemsetAsync(d_out, 0, sizeof(float), stream);
  gold_kernel<<<BB, 256, 0, stream>>>(em, tags, mask, trans, gold);
  part_kernel<<<2 * BB, 64, 0, stream>>>(em, mask, trans, alpha, beta);
  combine_kernel<<<BB, TT, 0, stream>>>(alpha, beta, gold, out);
}

// Round 2
// 378.517 us; speedup vs baseline: 1.2133x; 1.2133x over previous
//
#include <hip/hip_runtime.h>

#define BB 512
#define SS 1024
#define TT 64

__device__ __forceinline__ float wmax64(float v) {
#pragma unroll
  for (int off = 32; off > 0; off >>= 1) v = fmaxf(v, __shfl_xor(v, off, 64));
  return v;
}
__device__ __forceinline__ float wsum64(float v) {
#pragma unroll
  for (int off = 32; off > 0; off >>= 1) v += __shfl_xor(v, off, 64);
  return v;
}

// One recurrence step, linear domain.
// fwd (DIR=0): s_j = sum_i p_i E_ij ; p' = s * f * inv   (f = exp(e*mk))
// bwd (DIR=1): t_j = p_j * f_j * inv ; p'_i = sum_j E_ij t_j
// inv = 1/r from PREVIOUS step (delayed normalization, off critical path).
template <int DIR>
__device__ __forceinline__ void crf_step(float e, float mk, float& p, float& inv,
                                         float& Lacc, float& lastlg,
                                         const float E[TT], float* bc) {
  float f = __expf(e * mk);
  float bval = (DIR == 1) ? p * (f * inv) : p;
  bc[threadIdx.x] = bval;
  __builtin_amdgcn_wave_barrier();
  const float4* bq = (const float4*)bc;
  float a0 = 0.f, a1 = 0.f, a2 = 0.f, a3 = 0.f;
#pragma unroll
  for (int g = 0; g < 16; ++g) {
    float4 q = bq[g];
    a0 = fmaf(q.x, E[4 * g + 0], a0);
    a1 = fmaf(q.y, E[4 * g + 1], a1);
    a2 = fmaf(q.z, E[4 * g + 2], a2);
    a3 = fmaf(q.w, E[4 * g + 3], a3);
  }
  float s = (a0 + a1) + (a2 + a3);
  p = (DIR == 0) ? s * (f * inv) : s;
  // normalization bookkeeping for NEXT step (off critical path)
  float rn = __int_as_float(__builtin_amdgcn_readfirstlane(__float_as_int(s)));
  inv = __builtin_amdgcn_rcpf(rn);
  float lg = __logf(rn);
  Lacc += lg;
  lastlg = lg;
}

template <int DIR>
__device__ __forceinline__ void part_run(int b, int lane, const float* __restrict__ em,
                                         const float* __restrict__ mask,
                                         const float* __restrict__ trans,
                                         float* __restrict__ outv, float* bc) {
  // Per-lane E fragment: fwd lane j holds column E[i][j]; bwd lane i holds row E[i][j].
  float E[TT];
#pragma unroll
  for (int i = 0; i < TT; i++)
    E[i] = __expf(DIR == 0 ? trans[i * TT + lane] : trans[lane * TT + i]);

  const float* emb = em + (size_t)b * SS * TT;
  const float* mkb = mask + (size_t)b * SS;

  constexpr int NST = (DIR == 0) ? (SS / 2 - 1) : (SS / 2);  // 511 fwd, 512 bwd
  constexpr int S0 = (DIR == 0) ? 1 : (SS - 1);
  constexpr int SD = (DIR == 0) ? 1 : -1;
  constexpr int NG8 = NST / 8;    // full groups of 8 steps
  constexpr int TAIL8 = NST & 7;  // 7 fwd, 0 bwd

  float p = (DIR == 0) ? __expf(emb[lane] * mkb[0]) : 1.0f;
  float inv = 1.0f, Lacc = 0.0f, lastlg = 0.0f;

  // 8-deep emission prefetch (coalesced: lane j reads em[b][s][j])
  float ebuf[8];
#pragma unroll
  for (int k = 0; k < 8; ++k) ebuf[k] = emb[(S0 + SD * k) * TT + lane];
  const float* ep = emb + (ptrdiff_t)(S0 + SD * 8) * TT + lane;

  // mask: one coalesced vector load per 64 steps, broadcast via readlane
  float mv = 0.f;
  for (int t8 = 0; t8 < NG8; ++t8) {
    if ((t8 & 7) == 0) mv = mkb[S0 + SD * (t8 * 8 + lane)];
    int base = (t8 & 7) * 8;
#pragma unroll
    for (int k = 0; k < 8; ++k) {
      float e = ebuf[k];
      ebuf[k] = *ep;  // prefetch step t+8; always in-bounds (fwd s<=519, bwd s>=504)
      ep += SD * TT;
      float mk = __int_as_float(
          __builtin_amdgcn_readlane(__float_as_int(mv), base + k));
      crf_step<DIR>(e, mk, p, inv, Lacc, lastlg, E, bc);
    }
  }
  if constexpr (TAIL8 > 0) {
#pragma unroll
    for (int k = 0; k < TAIL8; ++k) {
      float e = ebuf[k];
      float mk = __int_as_float(
          __builtin_amdgcn_readlane(__float_as_int(mv), (NG8 & 7) * 8 + k));
      crf_step<DIR>(e, mk, p, inv, Lacc, lastlg, E, bc);
    }
  }

  outv[b * TT + lane] = __logf(p) + (Lacc - lastlg);
}

// Fused: blocks [0, 1024) = partition fwd/bwd; blocks [1024, 3072) = gold score
__global__ void fused_kernel(const float* __restrict__ em, const int* __restrict__ tags,
                             const float* __restrict__ mask, const float* __restrict__ trans,
                             float* __restrict__ alpha, float* __restrict__ beta,
                             float* __restrict__ gpart) {
  __shared__ __align__(16) float bc[TT];
  const int lane = threadIdx.x;
  const int bid = blockIdx.x;
  if (bid < 2 * BB) {
    const int b = bid >> 1;
    if ((bid & 1) == 0)
      part_run<0>(b, lane, em, mask, trans, alpha, bc);
    else
      part_run<1>(b, lane, em, mask, trans, beta, bc);
  } else {
    const int gid = bid - 2 * BB;  // 0..2047
    const int b = gid >> 2, q = gid & 3;
    const int* tg = tags + b * SS;
    const float* mkb = mask + (size_t)b * SS;
    const float* emb = em + (size_t)b * SS * TT;
    float part = 0.f;
#pragma unroll
    for (int i = 0; i < 4; ++i) {
      int s = q * 256 + i * 64 + lane;
      int t1 = tg[s];
      float e = emb[s * TT + t1];
      float contrib = (s == 0) ? e : (trans[t1 * TT + tg[s - 1]] + e);
      part = fmaf(contrib, mkb[s], part);
    }
    part = wsum64(part);
    if (lane == 0) gpart[gid] = part;
  }
}

__global__ void combine_kernel(const float* __restrict__ alpha, const float* __restrict__ beta,
                               const float* __restrict__ gpart, float* __restrict__ out) {
  const int b = blockIdx.x;
  const int j = threadIdx.x;
  float v = alpha[b * TT + j] + beta[b * TT + j];
  float m = wmax64(v);
  float e = __expf(v - m);
  e = wsum64(e);
  if (j == 0) {
    float Z = m + __logf(e);
    float g = gpart[4 * b] + gpart[4 * b + 1] + gpart[4 * b + 2] + gpart[4 * b + 3];
    atomicAdd(out, (Z - g) * (1.0f / (float)BB));
  }
}

extern "C" void kernel_launch(void* const* d_in, const int* in_sizes, int n_in,
                              void* d_out, int out_size, void* d_ws, size_t ws_size,
                              hipStream_t stream) {
  const float* em = (const float*)d_in[0];
  const int* tags = (const int*)d_in[1];
  const float* mask = (const float*)d_in[2];
  const float* trans = (const float*)d_in[3];
  float* out = (float*)d_out;

  float* alpha = (float*)d_ws;          // 512*64
  float* beta = alpha + BB * TT;        // 512*64
  float* gpart = beta + BB * TT;        // 2048

  hipMemsetAsync(d_out, 0, sizeof(float), stream);
  fused_kernel<<<2 * BB + 4 * BB, TT, 0, stream>>>(em, tags, mask, trans, alpha, beta, gpart);
  combine_kernel<<<BB, TT, 0, stream>>>(alpha, beta, gpart, out);
}

// Round 3
// 378.384 us; speedup vs baseline: 1.2137x; 1.0004x over previous
//
#include <hip/hip_runtime.h>

#define BB 512
#define SS 1024
#define TT 64

__device__ __forceinline__ float wsum64(float v) {
#pragma unroll
  for (int off = 32; off > 0; off >>= 1) v += __shfl_xor(v, off, 64);
  return v;
}

// One recurrence step, linear domain.
// fwd (DIR=0): s_j = sum_i p_i E_ij ; p' = s * f * inv   (f = exp(e*mk))
// bwd (DIR=1): t_j = p_j * f_j * inv ; p'_i = sum_j E_ij t_j
// inv = 1/r from PREVIOUS step (delayed normalization, off critical path).
template <int DIR>
__device__ __forceinline__ void crf_step(float e, float mk, float& p, float& inv,
                                         float& Lacc, float& lastlg,
                                         const float E[TT], float* bc) {
  float f = __expf(e * mk);
  float bval = (DIR == 1) ? p * (f * inv) : p;
  bc[threadIdx.x] = bval;
  __builtin_amdgcn_wave_barrier();
  const float4* bq = (const float4*)bc;
  float a0 = 0.f, a1 = 0.f, a2 = 0.f, a3 = 0.f;
#pragma unroll
  for (int g = 0; g < 16; ++g) {
    float4 q = bq[g];
    a0 = fmaf(q.x, E[4 * g + 0], a0);
    a1 = fmaf(q.y, E[4 * g + 1], a1);
    a2 = fmaf(q.z, E[4 * g + 2], a2);
    a3 = fmaf(q.w, E[4 * g + 3], a3);
  }
  float s = (a0 + a1) + (a2 + a3);
  p = (DIR == 0) ? s * (f * inv) : s;
  // normalization bookkeeping for NEXT step (off critical path)
  float rn = __int_as_float(__builtin_amdgcn_readfirstlane(__float_as_int(s)));
  inv = __builtin_amdgcn_rcpf(rn);
  float lg = __logf(rn);
  Lacc += lg;
  lastlg = lg;
}

template <int DIR>
__device__ __forceinline__ void part_run(int b, int lane, const float* __restrict__ em,
                                         const float* __restrict__ mask,
                                         const float* __restrict__ trans,
                                         float* __restrict__ outv, float* bc) {
  // Per-lane E fragment: fwd lane j holds column E[i][j]; bwd lane i holds row E[i][j].
  // MUST stay in VGPRs: kernel has __launch_bounds__(64,1) -> 512-VGPR budget.
  float E[TT];
#pragma unroll
  for (int i = 0; i < TT; i++)
    E[i] = __expf(DIR == 0 ? trans[i * TT + lane] : trans[lane * TT + i]);

  const float* emb = em + (size_t)b * SS * TT;
  const float* mkb = mask + (size_t)b * SS;

  constexpr int NST = (DIR == 0) ? (SS / 2 - 1) : (SS / 2);  // 511 fwd, 512 bwd
  constexpr int S0 = (DIR == 0) ? 1 : (SS - 1);
  constexpr int SD = (DIR == 0) ? 1 : -1;
  constexpr int NG8 = NST / 8;    // full groups of 8 steps
  constexpr int TAIL8 = NST & 7;  // 7 fwd, 0 bwd

  float p = (DIR == 0) ? __expf(emb[lane] * mkb[0]) : 1.0f;
  float inv = 1.0f, Lacc = 0.0f, lastlg = 0.0f;

  // 8-deep emission prefetch (coalesced: lane j reads em[b][s][j])
  float ebuf[8];
#pragma unroll
  for (int k = 0; k < 8; ++k) ebuf[k] = emb[(S0 + SD * k) * TT + lane];
  const float* ep = emb + (ptrdiff_t)(S0 + SD * 8) * TT + lane;

  // mask: one coalesced vector load per 64 steps, broadcast via readlane
  float mv = 0.f;
  for (int t8 = 0; t8 < NG8; ++t8) {
    if ((t8 & 7) == 0) mv = mkb[S0 + SD * (t8 * 8 + lane)];
    int base = (t8 & 7) * 8;
#pragma unroll
    for (int k = 0; k < 8; ++k) {
      float e = ebuf[k];
      ebuf[k] = *ep;  // prefetch step t+8; always in-bounds (fwd s<=519, bwd s>=504)
      ep += SD * TT;
      float mk = __int_as_float(
          __builtin_amdgcn_readlane(__float_as_int(mv), base + k));
      crf_step<DIR>(e, mk, p, inv, Lacc, lastlg, E, bc);
    }
  }
  if constexpr (TAIL8 > 0) {
#pragma unroll
    for (int k = 0; k < TAIL8; ++k) {
      float e = ebuf[k];
      float mk = __int_as_float(
          __builtin_amdgcn_readlane(__float_as_int(mv), (NG8 & 7) * 8 + k));
      crf_step<DIR>(e, mk, p, inv, Lacc, lastlg, E, bc);
    }
  }

  outv[b * TT + lane] = __logf(p) + (Lacc - lastlg);
}

// Fused: blocks [0, 1024) = partition fwd/bwd; blocks [1024, 3072) = gold score
__global__ void __launch_bounds__(64, 1)
    fused_kernel(const float* __restrict__ em, const int* __restrict__ tags,
                 const float* __restrict__ mask, const float* __restrict__ trans,
                 float* __restrict__ alpha, float* __restrict__ beta,
                 float* __restrict__ gpart) {
  __shared__ __align__(16) float bc[TT];
  const int lane = threadIdx.x;
  const int bid = blockIdx.x;
  if (bid < 2 * BB) {
    const int b = bid >> 1;
    if ((bid & 1) == 0)
      part_run<0>(b, lane, em, mask, trans, alpha, bc);
    else
      part_run<1>(b, lane, em, mask, trans, beta, bc);
  } else {
    const int gid = bid - 2 * BB;  // 0..2047
    const int b = gid >> 2, q = gid & 3;
    const int* tg = tags + b * SS;
    const float* mkb = mask + (size_t)b * SS;
    const float* emb = em + (size_t)b * SS * TT;
    float part = 0.f;
#pragma unroll
    for (int i = 0; i < 4; ++i) {
      int s = q * 256 + i * 64 + lane;
      int t1 = tg[s];
      float e = emb[s * TT + t1];
      float contrib = (s == 0) ? e : (trans[t1 * TT + tg[s - 1]] + e);
      part = fmaf(contrib, mkb[s], part);
    }
    part = wsum64(part);
    if (lane == 0) gpart[gid] = part;
  }
}

// Single block, 512 threads: thread b computes Z_b - gold_b, block-reduces, writes mean.
__global__ void combine_kernel(const float* __restrict__ alpha, const float* __restrict__ beta,
                               const float* __restrict__ gpart, float* __restrict__ out) {
  const int b = threadIdx.x;  // 0..511
  const float* av = alpha + b * TT;
  const float* bv = beta + b * TT;
  float m = -3.4e38f, s = 0.f;
#pragma unroll 8
  for (int j = 0; j < TT; ++j) {
    float v = av[j] + bv[j];
    float nm = fmaxf(m, v);
    s = s * __expf(m - nm) + __expf(v - nm);
    m = nm;
  }
  float Z = m + __logf(s);
  float g = gpart[4 * b] + gpart[4 * b + 1] + gpart[4 * b + 2] + gpart[4 * b + 3];
  float val = Z - g;
  val = wsum64(val);
  __shared__ float red[8];
  if ((threadIdx.x & 63) == 0) red[threadIdx.x >> 6] = val;
  __syncthreads();
  if (threadIdx.x == 0) {
    float t = 0.f;
#pragma unroll
    for (int w = 0; w < 8; ++w) t += red[w];
    out[0] = t * (1.0f / (float)BB);
  }
}

extern "C" void kernel_launch(void* const* d_in, const int* in_sizes, int n_in,
                              void* d_out, int out_size, void* d_ws, size_t ws_size,
                              hipStream_t stream) {
  const float* em = (const float*)d_in[0];
  const int* tags = (const int*)d_in[1];
  const float* mask = (const float*)d_in[2];
  const float* trans = (const float*)d_in[3];
  float* out = (float*)d_out;

  float* alpha = (float*)d_ws;          // 512*64
  float* beta = alpha + BB * TT;        // 512*64
  float* gpart = beta + BB * TT;        // 2048

  fused_kernel<<<2 * BB + 4 * BB, TT, 0, stream>>>(em, tags, mask, trans, alpha, beta, gpart);
  combine_kernel<<<1, BB, 0, stream>>>(alpha, beta, gpart, out);
}

// Round 4
// 326.192 us; speedup vs baseline: 1.4079x; 1.1600x over previous
//
#include <hip/hip_runtime.h>

#define BB 512
#define SS 1024
#define TT 64

__device__ __forceinline__ float wsum64(float v) {
#pragma unroll
  for (int off = 32; off > 0; off >>= 1) v += __shfl_xor(v, off, 64);
  return v;
}

// X-macro list: apply M(i) for i = 0..63
#define E_LIST(M) \
  M(0) M(1) M(2) M(3) M(4) M(5) M(6) M(7) \
  M(8) M(9) M(10) M(11) M(12) M(13) M(14) M(15) \
  M(16) M(17) M(18) M(19) M(20) M(21) M(22) M(23) \
  M(24) M(25) M(26) M(27) M(28) M(29) M(30) M(31) \
  M(32) M(33) M(34) M(35) M(36) M(37) M(38) M(39) \
  M(40) M(41) M(42) M(43) M(44) M(45) M(46) M(47) \
  M(48) M(49) M(50) M(51) M(52) M(53) M(54) M(55) \
  M(56) M(57) M(58) M(59) M(60) M(61) M(62) M(63)

#define RL(i) __int_as_float(__builtin_amdgcn_readlane(pb_, (i)))

#define FMA4(i0, i1, i2, i3)          \
  a0 = fmaf(RL(i0), E##i0, a0);       \
  a1 = fmaf(RL(i1), E##i1, a1);       \
  a2 = fmaf(RL(i2), E##i2, a2);       \
  a3 = fmaf(RL(i3), E##i3, a3);

#define FMA_ALL                      \
  FMA4(0, 1, 2, 3)                   \
  FMA4(4, 5, 6, 7)                   \
  FMA4(8, 9, 10, 11)                 \
  FMA4(12, 13, 14, 15)               \
  FMA4(16, 17, 18, 19)               \
  FMA4(20, 21, 22, 23)               \
  FMA4(24, 25, 26, 27)               \
  FMA4(28, 29, 30, 31)               \
  FMA4(32, 33, 34, 35)               \
  FMA4(36, 37, 38, 39)               \
  FMA4(40, 41, 42, 43)               \
  FMA4(44, 45, 46, 47)               \
  FMA4(48, 49, 50, 51)               \
  FMA4(52, 53, 54, 55)               \
  FMA4(56, 57, 58, 59)               \
  FMA4(60, 61, 62, 63)

// One recurrence step, linear domain, delayed scalar normalization.
// fwd (DIR=0): broadcast p; s_j = sum_i p_i E_ij ; p' = s * (f_j * inv)
// bwd (DIR=1): broadcast t_j = p_j * f_j * inv ; p'_i = sum_j E_ij t_j
// inv = 1/readfirstlane(s) from the PREVIOUS step (off critical path).
#define CRF_STEP(ev, mkv)                                                           \
  do {                                                                              \
    float f_ = __expf((ev) * (mkv));                                                \
    float pv_ = (DIR == 1) ? p * (f_ * inv) : p;                                    \
    int pb_ = __float_as_int(pv_);                                                  \
    float a0 = 0.f, a1 = 0.f, a2 = 0.f, a3 = 0.f;                                   \
    FMA_ALL                                                                         \
    float s_ = (a0 + a1) + (a2 + a3);                                               \
    p = (DIR == 0) ? s_ * (f_ * inv) : s_;                                          \
    float rn_ = __int_as_float(__builtin_amdgcn_readfirstlane(__float_as_int(s_))); \
    inv = __builtin_amdgcn_rcpf(rn_);                                               \
    float lg_ = __logf(rn_);                                                        \
    Lacc += lg_;                                                                    \
    lastlg = lg_;                                                                   \
  } while (0)

template <int DIR>
__device__ __forceinline__ void part_run(int b, int lane, const float* __restrict__ em,
                                         const float* __restrict__ mask,
                                         const float* __restrict__ trans,
                                         float* __restrict__ outv) {
  // Per-lane E fragment as 64 NAMED scalars (never an array -> never scratch).
  // fwd lane j holds column E[i][j]; bwd lane i holds row E[i][j].
  const float* tp = trans + (DIR == 0 ? lane : lane * TT);
#define EINIT(i) float E##i = __expf((DIR == 0) ? tp[(i)*TT] : tp[(i)]);
  E_LIST(EINIT)
#undef EINIT

  const float* emb = em + (size_t)b * SS * TT;
  const float* mkb = mask + (size_t)b * SS;

  constexpr int NST = (DIR == 0) ? (SS / 2 - 1) : (SS / 2);  // 511 fwd, 512 bwd
  constexpr int S0 = (DIR == 0) ? 1 : (SS - 1);
  constexpr int SD = (DIR == 0) ? 1 : -1;
  constexpr int NG8 = NST / 8;    // full groups of 8 steps
  constexpr int TAIL8 = NST & 7;  // 7 fwd, 0 bwd

  float p = (DIR == 0) ? __expf(emb[lane] * mkb[0]) : 1.0f;
  float inv = 1.0f, Lacc = 0.0f, lastlg = 0.0f;

  // 8-deep emission prefetch (coalesced: lane j reads em[b][s][j])
  float ebuf[8];
#pragma unroll
  for (int k = 0; k < 8; ++k) ebuf[k] = emb[(S0 + SD * k) * TT + lane];
  const float* ep = emb + (ptrdiff_t)(S0 + SD * 8) * TT + lane;

  // mask: one coalesced vector load per 64 steps, broadcast via readlane
  float mv = 0.f;
  for (int t8 = 0; t8 < NG8; ++t8) {
    if ((t8 & 7) == 0) mv = mkb[S0 + SD * (t8 * 8 + lane)];
    int base = (t8 & 7) * 8;
#pragma unroll
    for (int k = 0; k < 8; ++k) {
      float e = ebuf[k];
      ebuf[k] = *ep;  // prefetch step t+8; always in-bounds (fwd s<=519, bwd s>=504)
      ep += SD * TT;
      float mk = __int_as_float(
          __builtin_amdgcn_readlane(__float_as_int(mv), base + k));
      CRF_STEP(e, mk);
    }
  }
  if constexpr (TAIL8 > 0) {
#pragma unroll
    for (int k = 0; k < TAIL8; ++k) {
      float e = ebuf[k];
      float mk = __int_as_float(
          __builtin_amdgcn_readlane(__float_as_int(mv), (NG8 & 7) * 8 + k));
      CRF_STEP(e, mk);
    }
  }

  outv[b * TT + lane] = __logf(p) + (Lacc - lastlg);
}

// Fused: blocks [0, 1024) = partition fwd/bwd; blocks [1024, 3072) = gold score
__global__ void __launch_bounds__(64, 1)
    fused_kernel(const float* __restrict__ em, const int* __restrict__ tags,
                 const float* __restrict__ mask, const float* __restrict__ trans,
                 float* __restrict__ alpha, float* __restrict__ beta,
                 float* __restrict__ gpart) {
  const int lane = threadIdx.x;
  const int bid = blockIdx.x;
  if (bid < 2 * BB) {
    const int b = bid >> 1;
    if ((bid & 1) == 0)
      part_run<0>(b, lane, em, mask, trans, alpha);
    else
      part_run<1>(b, lane, em, mask, trans, beta);
  } else {
    const int gid = bid - 2 * BB;  // 0..2047
    const int b = gid >> 2, q = gid & 3;
    const int* tg = tags + b * SS;
    const float* mkb = mask + (size_t)b * SS;
    const float* emb = em + (size_t)b * SS * TT;
    float part = 0.f;
#pragma unroll
    for (int i = 0; i < 4; ++i) {
      int s = q * 256 + i * 64 + lane;
      int t1 = tg[s];
      float e = emb[s * TT + t1];
      float contrib = (s == 0) ? e : (trans[t1 * TT + tg[s - 1]] + e);
      part = fmaf(contrib, mkb[s], part);
    }
    part = wsum64(part);
    if (lane == 0) gpart[gid] = part;
  }
}

// Single block, 512 threads: thread b computes Z_b - gold_b, block-reduces, writes mean.
__global__ void combine_kernel(const float* __restrict__ alpha, const float* __restrict__ beta,
                               const float* __restrict__ gpart, float* __restrict__ out) {
  const int b = threadIdx.x;  // 0..511
  const float* av = alpha + b * TT;
  const float* bv = beta + b * TT;
  float m = -3.4e38f, s = 0.f;
#pragma unroll 8
  for (int j = 0; j < TT; ++j) {
    float v = av[j] + bv[j];
    float nm = fmaxf(m, v);
    s = s * __expf(m - nm) + __expf(v - nm);
    m = nm;
  }
  float Z = m + __logf(s);
  float g = gpart[4 * b] + gpart[4 * b + 1] + gpart[4 * b + 2] + gpart[4 * b + 3];
  float val = Z - g;
  val = wsum64(val);
  __shared__ float red[8];
  if ((threadIdx.x & 63) == 0) red[threadIdx.x >> 6] = val;
  __syncthreads();
  if (threadIdx.x == 0) {
    float t = 0.f;
#pragma unroll
    for (int w = 0; w < 8; ++w) t += red[w];
    out[0] = t * (1.0f / (float)BB);
  }
}

extern "C" void kernel_launch(void* const* d_in, const int* in_sizes, int n_in,
                              void* d_out, int out_size, void* d_ws, size_t ws_size,
                              hipStream_t stream) {
  const float* em = (const float*)d_in[0];
  const int* tags = (const int*)d_in[1];
  const float* mask = (const float*)d_in[2];
  const float* trans = (const float*)d_in[3];
  float* out = (float*)d_out;

  float* alpha = (float*)d_ws;      // 512*64
  float* beta = alpha + BB * TT;    // 512*64
  float* gpart = beta + BB * TT;    // 2048

  fused_kernel<<<2 * BB + 4 * BB, TT, 0, stream>>>(em, tags, mask, trans, alpha, beta, gpart);
  combine_kernel<<<1, BB, 0, stream>>>(alpha, beta, gpart, out);
}